// Round 18
// baseline (603.045 us; speedup 1.0000x reference)
//
#include <hip/hip_runtime.h>
#include <hip/hip_bf16.h>

#define H_DIM 1024
#define I_DIM 2816
#define NE 8
#define T_TOK 8192
#define RMAX 17408

// control ws offsets (bytes)
#define WS_ROUTE_CNT 0
#define WS_PO        64
#define WS_TOP1      128
#define WS_PSUM      160
#define WS_RECIDX    256
#define WS_RECW0     33024
#define WS_RECW1     65792
#define WS_POS0      98560
#define WS_POS1      131328
#define WS_TOKID     164096

constexpr size_t WS_XG  = 1ull << 20;
constexpr size_t XG_SZ  = (size_t)RMAX * H_DIM * 2;      // 35.7 MB
constexpr size_t W_SZ   = (size_t)NE * I_DIM * H_DIM * 2; // 46.1 MB
constexpr size_t WS_WGB = WS_XG + XG_SZ;
constexpr size_t WS_WUB = WS_WGB + W_SZ;
constexpr size_t WS_WDB = WS_WUB + W_SZ;
constexpr size_t WS_ACT = WS_WDB + W_SZ;                  // 98 MB
constexpr size_t WS_Y   = WS_XG;                          // yseg overlays xg

typedef __attribute__((ext_vector_type(8))) short short8;
typedef __attribute__((ext_vector_type(4))) float f32x4;

#define GLOAD16(g, l) __builtin_amdgcn_global_load_lds( \
    (const __attribute__((address_space(1))) void*)(g), \
    (__attribute__((address_space(3))) void*)(l), 16, 0, 0)

static __device__ __forceinline__ short f2bf(float f) {
  return (short)__builtin_bit_cast(unsigned short, (__bf16)f);
}
static __device__ __forceinline__ float bf2f(short s) {
  return __builtin_bit_cast(float, ((unsigned)(unsigned short)s) << 16);
}

static __device__ __forceinline__ short8 pack8(const float* __restrict__ p) {
  float4 a = *(const float4*)p;
  float4 b = *(const float4*)(p + 4);
  short8 v;
  v[0] = f2bf(a.x); v[1] = f2bf(a.y); v[2] = f2bf(a.z); v[3] = f2bf(a.w);
  v[4] = f2bf(b.x); v[5] = f2bf(b.y); v[6] = f2bf(b.z); v[7] = f2bf(b.w);
  return v;
}

// ---------------- prep: wg+wu convert (blocks < 2*CONV1) + router ----------
#define W_ELEM ((size_t)NE * I_DIM * H_DIM)
#define W_CHUNK (W_ELEM / 8)                   // 2,883,584
#define CONV1 (int)(W_CHUNK / 256)             // 11,264 blocks per tensor
#define PREPB (2 * CONV1 + T_TOK / 4)

__global__ __launch_bounds__(256) void k_prep(const float* __restrict__ x,
                                              const float* __restrict__ gw,
                                              const float* __restrict__ wg,
                                              const float* __restrict__ wu,
                                              char* __restrict__ ws) {
  if (blockIdx.x < 2 * CONV1) {
    int which = blockIdx.x / CONV1;
    size_t off = ((size_t)(blockIdx.x - which * CONV1) * 256 + threadIdx.x) * 8;
    const float* src = which ? wu : wg;
    short* dst = (short*)(ws + (which ? WS_WUB : WS_WGB));
    *(short8*)(dst + off) = pack8(src + off);
    return;
  }
  int tid = threadIdx.x;
  int lane = tid & 63;
  int wv = tid >> 6;
  int t = (blockIdx.x - 2 * CONV1) * 4 + wv;

  float acc[NE];
#pragma unroll
  for (int e = 0; e < NE; ++e) acc[e] = 0.f;
  const float* xr = x + (size_t)t * H_DIM;
#pragma unroll
  for (int k = 0; k < H_DIM / 64; ++k) {
    float xv = xr[k * 64 + lane];
#pragma unroll
    for (int e = 0; e < NE; ++e) acc[e] += xv * gw[e * H_DIM + k * 64 + lane];
  }
#pragma unroll
  for (int e = 0; e < NE; ++e) {
#pragma unroll
    for (int off = 32; off; off >>= 1) acc[e] += __shfl_xor(acc[e], off);
  }

  __shared__ float s_ps[NE], s_c1[NE];
  __shared__ int s_rc[NE];
  if (tid < NE) { s_ps[tid] = 0.f; s_c1[tid] = 0.f; s_rc[tid] = 0; }
  __syncthreads();

  int* recIdx = (int*)(ws + WS_RECIDX);
  float* recW0 = (float*)(ws + WS_RECW0);
  float* recW1 = (float*)(ws + WS_RECW1);

  if (lane == 0) {
    float mx = acc[0];
#pragma unroll
    for (int e = 1; e < NE; ++e) mx = fmaxf(mx, acc[e]);
    float p[NE], s = 0.f;
#pragma unroll
    for (int e = 0; e < NE; ++e) { p[e] = expf(acc[e] - mx); s += p[e]; }
    float inv = 1.f / s;
#pragma unroll
    for (int e = 0; e < NE; ++e) p[e] *= inv;
    int i0 = 0;
#pragma unroll
    for (int e = 1; e < NE; ++e) if (p[e] > p[i0]) i0 = e;
    int i1 = (i0 == 0) ? 1 : 0;
#pragma unroll
    for (int e = 0; e < NE; ++e) if (e != i0 && p[e] > p[i1]) i1 = e;
    float w0 = p[i0], w1 = p[i1];
    float sm = fmaxf(w0 + w1, 1e-8f);
    w0 /= sm; w1 /= sm;
    recIdx[t] = i0 | (i1 << 8);
    recW0[t] = w0;
    recW1[t] = w1;
    atomicAdd(&s_c1[i0], 1.f);
#pragma unroll
    for (int e = 0; e < NE; ++e) atomicAdd(&s_ps[e], p[e]);
    atomicAdd(&s_rc[i0], 1);
    atomicAdd(&s_rc[i1], 1);
  }
  __syncthreads();
  if (tid < NE) {
    atomicAdd((float*)(ws + WS_PSUM) + tid, s_ps[tid]);
    atomicAdd((float*)(ws + WS_TOP1) + tid, s_c1[tid]);
    atomicAdd((int*)(ws + WS_ROUTE_CNT) + tid, s_rc[tid]);
  }
}

// ---------------- build: offsets + aux + assign (merged, single block) -----
__global__ __launch_bounds__(256) void k_build(char* __restrict__ ws,
                                               float* __restrict__ out_aux) {
  __shared__ int s_po[NE];
  __shared__ int s_cur[NE];
  int tid = threadIdx.x;
  if (tid == 0) {
    int* rc = (int*)(ws + WS_ROUTE_CNT);
    int* po = (int*)(ws + WS_PO);
    int acc = 0;
    for (int e = 0; e < NE; ++e) {
      s_po[e] = acc; po[e] = acc;
      acc += ((rc[e] + 127) / 128) * 128;
    }
    po[NE] = acc;
    float* c1 = (float*)(ws + WS_TOP1);
    float* ps = (float*)(ws + WS_PSUM);
    float aux = 0.f;
    for (int e = 0; e < NE; ++e)
      aux += (c1[e] / (float)T_TOK) * (ps[e] / (float)T_TOK);
    out_aux[0] = aux * (float)NE;
  }
  if (tid < NE) s_cur[tid] = 0;
  __syncthreads();

  int* recIdx = (int*)(ws + WS_RECIDX);
  int* tokid = (int*)(ws + WS_TOKID);
  int* pos0 = (int*)(ws + WS_POS0);
  int* pos1 = (int*)(ws + WS_POS1);
  for (int t = tid; t < T_TOK; t += 256) {
    int rec = recIdx[t];
    int e0 = rec & 255, e1 = (rec >> 8) & 255;
    int p0 = atomicAdd(&s_cur[e0], 1);
    int r0 = s_po[e0] + p0;
    tokid[r0] = t; pos0[t] = r0;
    int p1 = atomicAdd(&s_cur[e1], 1);
    int r1 = s_po[e1] + p1;
    tokid[r1] = t; pos1[t] = r1;
  }
}

// ---------------- gather x -> bf16 permuted (zero-padded) -------------------
__global__ __launch_bounds__(256) void k_gather(const float* __restrict__ x,
                                                char* __restrict__ ws) {
  const int* po = (const int*)(ws + WS_PO);
  const int* rc = (const int*)(ws + WS_ROUTE_CNT);
  const int* tokid = (const int*)(ws + WS_TOKID);
  short* xg = (short*)(ws + WS_XG);
  int r = blockIdx.x * 8 + (threadIdx.x >> 5);
  if (r >= po[NE]) return;
  int e = 0;
#pragma unroll
  for (int q = 1; q < NE; ++q) if (r >= po[q]) e = q;
  int l = r - po[e];
  int c0 = (threadIdx.x & 31) * 32;
  short* dst = xg + (size_t)r * H_DIM + c0;
  if (l < rc[e]) {
    const float* src = x + (size_t)tokid[r] * H_DIM + c0;
#pragma unroll
    for (int j = 0; j < 4; ++j) *(short8*)(dst + j * 8) = pack8(src + j * 8);
  } else {
    short8 z = (short8)0;
#pragma unroll
    for (int j = 0; j < 4; ++j) *(short8*)(dst + j * 8) = z;
  }
}

// ============ fused FFN1: act = silu(xg@wg^T) * (xg@wu^T) (R17, frozen) ====
template <int NCONV>
__global__ __launch_bounds__(256, 2) void k_ffn1(const short* __restrict__ A,
                                                 const short* __restrict__ Bg_,
                                                 const short* __restrict__ Bu_,
                                                 short* __restrict__ act,
                                                 const float* __restrict__ cw,
                                                 char* __restrict__ ws) {
  constexpr int GEMMB = 8 * 17 * (I_DIM / 128);
  if (NCONV > 0 && blockIdx.x >= GEMMB) {
    int cidx = blockIdx.x - GEMMB;
    size_t off = ((size_t)cidx * 256 + threadIdx.x) * 8;
    short* dst = (short*)(ws + WS_WDB);
    *(short8*)(dst + off) = pack8(cw + off);
    return;
  }

  const int* po = (const int*)(ws + WS_PO);
  int poNE = po[NE];

  int idx = blockIdx.x;
  int xcd = idx & 7, j = idx >> 3;
  int nt = j / 17;
  int rt = xcd * 17 + (j - nt * 17);

  int r0 = rt * 128;
  if (r0 >= poNE) return;
  int e = 0;
#pragma unroll
  for (int qe = 1; qe < NE; ++qe) if (r0 >= po[qe]) e = qe;

  const short* Ab = A + (size_t)r0 * H_DIM;
  const short* Gb = Bg_ + (size_t)e * ((size_t)I_DIM * H_DIM) + (size_t)(nt * 128) * H_DIM;
  const short* Ub = Bu_ + (size_t)e * ((size_t)I_DIM * H_DIM) + (size_t)(nt * 128) * H_DIM;

  __shared__ __align__(16) short As[128 * 64];
  __shared__ __align__(16) short Gs[128 * 64];
  __shared__ __align__(16) short Us[128 * 64];

  int tid = threadIdx.x, lane = tid & 63, w = tid >> 6;
  int wr = (w >> 1) * 64, wc = (w & 1) * 64;
  int fr = lane & 15, kq = (lane >> 4) * 8;
  int srow = tid >> 3, scol = (tid & 7) * 8;

  f32x4 accg[4][4], accu[4][4];
  f32x4 z4 = {0.f, 0.f, 0.f, 0.f};
#pragma unroll
  for (int m = 0; m < 4; ++m)
#pragma unroll
    for (int n = 0; n < 4; ++n) { accg[m][n] = z4; accu[m][n] = z4; }

  for (int kk = 0; kk < H_DIM; kk += 64) {
#pragma unroll
    for (int c = 0; c < 4; ++c) {
      GLOAD16(Ab + (size_t)(c * 32 + srow) * H_DIM + kk + scol, &As[c * 2048 + tid * 8]);
      GLOAD16(Gb + (size_t)(c * 32 + srow) * H_DIM + kk + scol, &Gs[c * 2048 + tid * 8]);
      GLOAD16(Ub + (size_t)(c * 32 + srow) * H_DIM + kk + scol, &Us[c * 2048 + tid * 8]);
    }
    __syncthreads();
#pragma unroll
    for (int ks = 0; ks < 2; ++ks) {
      short8 af[4];
#pragma unroll
      for (int m = 0; m < 4; ++m)
        af[m] = *(const short8*)&As[(wr + m * 16 + fr) * 64 + ks * 32 + kq];
#pragma unroll
      for (int n = 0; n < 4; ++n) {
        short8 bg = *(const short8*)&Gs[(wc + n * 16 + fr) * 64 + ks * 32 + kq];
        short8 bu = *(const short8*)&Us[(wc + n * 16 + fr) * 64 + ks * 32 + kq];
#pragma unroll
        for (int m = 0; m < 4; ++m) {
          accg[m][n] = __builtin_amdgcn_mfma_f32_16x16x32_bf16(af[m], bg, accg[m][n], 0, 0, 0);
          accu[m][n] = __builtin_amdgcn_mfma_f32_16x16x32_bf16(af[m], bu, accu[m][n], 0, 0, 0);
        }
      }
    }
    __syncthreads();
  }

  int q4 = (lane >> 4) * 4;
#pragma unroll
  for (int m = 0; m < 4; ++m) {
#pragma unroll
    for (int n = 0; n < 4; ++n) {
      int col = nt * 128 + wc + n * 16 + fr;
#pragma unroll
      for (int j2 = 0; j2 < 4; ++j2) {
        float g = accg[m][n][j2];
        float u = accu[m][n][j2];
        act[(size_t)(r0 + wr + m * 16 + q4 + j2) * I_DIM + col] =
            f2bf(g / (1.f + expf(-g)) * u);
      }
    }
  }
}

// ============ down GEMM widened: 128x256, 256 thr, 2 blocks/CU =============
// Same mechanism as ffn1's win: 12 gloads/thread/K-step feed 256 MFMA/block
// (1.33x MFMA:staged-byte vs 128^2). acc[4][8] = 128 AGPR + ~64 VGPR fits
// (256,2); LDS 48 KB -> 2 independent blocks/CU (the session law: the
// 2-phase family needs >=2 blocks/CU -- R12's failure was 512thr/1-block).
__global__ __launch_bounds__(256, 2) void k_down(const short* __restrict__ A,
                                                 const short* __restrict__ Bw,
                                                 short* __restrict__ Cb,
                                                 char* __restrict__ ws) {
  const int* po = (const int*)(ws + WS_PO);
  int poNE = po[NE];

  int idx = blockIdx.x;
  int xcd = idx & 7, j = idx >> 3;       // j in [0, 17 * H_DIM/256)
  int nt = j / 17;
  int rt = xcd * 17 + (j - nt * 17);

  int r0 = rt * 128;
  if (r0 >= poNE) return;
  int e = 0;
#pragma unroll
  for (int qe = 1; qe < NE; ++qe) if (r0 >= po[qe]) e = qe;

  const short* Ab = A + (size_t)r0 * I_DIM;
  const short* Bb = Bw + (size_t)e * ((size_t)H_DIM * I_DIM) + (size_t)(nt * 256) * I_DIM;

  __shared__ __align__(16) short As[128 * 64];   // 16 KB
  __shared__ __align__(16) short Bs[256 * 64];   // 32 KB

  int tid = threadIdx.x, lane = tid & 63, w = tid >> 6;
  int wr = (w >> 1) * 64, wc = (w & 1) * 128;    // 2M x 2N wave grid, N=128/wave
  int fr = lane & 15, kq = (lane >> 4) * 8;
  int srow = tid >> 3, scol = (tid & 7) * 8;

  f32x4 acc[4][8];
  f32x4 z4 = {0.f, 0.f, 0.f, 0.f};
#pragma unroll
  for (int m = 0; m < 4; ++m)
#pragma unroll
    for (int n = 0; n < 8; ++n) acc[m][n] = z4;

  for (int kk = 0; kk < I_DIM; kk += 64) {
#pragma unroll
    for (int c = 0; c < 4; ++c)
      GLOAD16(Ab + (size_t)(c * 32 + srow) * I_DIM + kk + scol, &As[c * 2048 + tid * 8]);
#pragma unroll
    for (int c = 0; c < 8; ++c)
      GLOAD16(Bb + (size_t)(c * 32 + srow) * I_DIM + kk + scol, &Bs[c * 2048 + tid * 8]);
    __syncthreads();
#pragma unroll
    for (int ks = 0; ks < 2; ++ks) {
      short8 af[4];
#pragma unroll
      for (int m = 0; m < 4; ++m)
        af[m] = *(const short8*)&As[(wr + m * 16 + fr) * 64 + ks * 32 + kq];
#pragma unroll
      for (int n = 0; n < 8; ++n) {
        short8 bf_ = *(const short8*)&Bs[(wc + n * 16 + fr) * 64 + ks * 32 + kq];
#pragma unroll
        for (int m = 0; m < 4; ++m)
          acc[m][n] = __builtin_amdgcn_mfma_f32_16x16x32_bf16(af[m], bf_, acc[m][n], 0, 0, 0);
      }
    }
    __syncthreads();
  }

  int q4 = (lane >> 4) * 4;
#pragma unroll
  for (int m = 0; m < 4; ++m) {
#pragma unroll
    for (int n = 0; n < 8; ++n) {
      int col = nt * 256 + wc + n * 16 + fr;
#pragma unroll
      for (int j2 = 0; j2 < 4; ++j2)
        Cb[(size_t)(r0 + wr + m * 16 + q4 + j2) * H_DIM + col] = f2bf(acc[m][n][j2]);
    }
  }
}

// ---------------- combine: out[t] = w0*y[pos0] + w1*y[pos1] ----------------
__global__ __launch_bounds__(256) void k_combine(float* __restrict__ out,
                                                 char* __restrict__ ws) {
  int t = blockIdx.x * 4 + (threadIdx.x >> 6);
  int lane = threadIdx.x & 63;
  const float* recW0 = (const float*)(ws + WS_RECW0);
  const float* recW1 = (const float*)(ws + WS_RECW1);
  const int* pos0 = (const int*)(ws + WS_POS0);
  const int* pos1 = (const int*)(ws + WS_POS1);
  const short* yseg = (const short*)(ws + WS_Y);

  float w0 = recW0[t], w1 = recW1[t];
  const short* y0 = yseg + (size_t)pos0[t] * H_DIM + lane * 16;
  const short* y1 = yseg + (size_t)pos1[t] * H_DIM + lane * 16;
  float* op = out + (size_t)t * H_DIM + lane * 16;

  short8 a0 = *(const short8*)y0;
  short8 a1 = *(const short8*)(y0 + 8);
  short8 b0 = *(const short8*)y1;
  short8 b1 = *(const short8*)(y1 + 8);
#pragma unroll
  for (int j = 0; j < 8; ++j)
    op[j] = w0 * bf2f(a0[j]) + w1 * bf2f(b0[j]);
#pragma unroll
  for (int j = 0; j < 8; ++j)
    op[8 + j] = w0 * bf2f(a1[j]) + w1 * bf2f(b1[j]);
}

extern "C" void kernel_launch(void* const* d_in, const int* in_sizes, int n_in,
                              void* d_out, int out_size, void* d_ws, size_t ws_size,
                              hipStream_t stream) {
  const float* x  = (const float*)d_in[0];
  const float* gw = (const float*)d_in[1];
  const float* wg = (const float*)d_in[2];
  const float* wu = (const float*)d_in[3];
  const float* wd = (const float*)d_in[4];
  float* out = (float*)d_out;
  char* ws = (char*)d_ws;

  hipMemsetAsync(ws, 0, 256, stream);

  const short* xg  = (const short*)(ws + WS_XG);
  const short* wgb = (const short*)(ws + WS_WGB);
  const short* wub = (const short*)(ws + WS_WUB);
  const short* wdb = (const short*)(ws + WS_WDB);
  short* act  = (short*)(ws + WS_ACT);
  short* yseg = (short*)(ws + WS_Y);

  // prep: wg + wu convert + router (wd rides on FFN1)
  k_prep<<<PREPB, 256, 0, stream>>>(x, gw, wg, wu, ws);
  k_build<<<1, 256, 0, stream>>>(ws, out + (size_t)T_TOK * H_DIM);
  k_gather<<<RMAX / 8, 256, 0, stream>>>(x, ws);

  // fused FFN1: act = silu(xg@wg^T)*(xg@wu^T)  (+ trailing wd convert)
  k_ffn1<1><<<8 * 17 * (I_DIM / 128) + CONV1, 256, 0, stream>>>(
      xg, wgb, wub, act, wd, ws);
  // down (widened 128x256): yseg = act @ wd^T
  k_down<<<8 * 17 * (H_DIM / 256), 256, 0, stream>>>(act, wdb, yseg, ws);

  k_combine<<<T_TOK / 4, 256, 0, stream>>>(out, ws);
}

// Round 19
// 579.326 us; speedup vs baseline: 1.0409x; 1.0409x over previous
//
#include <hip/hip_runtime.h>
#include <hip/hip_bf16.h>

#define H_DIM 1024
#define I_DIM 2816
#define NE 8
#define T_TOK 8192
#define RMAX 17408

// control ws offsets (bytes)
#define WS_ROUTE_CNT 0
#define WS_PO        64
#define WS_TOP1      128
#define WS_PSUM      160
#define WS_RECIDX    256
#define WS_RECW0     33024
#define WS_RECW1     65792
#define WS_POS0      98560
#define WS_POS1      131328
#define WS_TOKID     164096

constexpr size_t WS_XG  = 1ull << 20;
constexpr size_t XG_SZ  = (size_t)RMAX * H_DIM * 2;      // 35.7 MB
constexpr size_t W_SZ   = (size_t)NE * I_DIM * H_DIM * 2; // 46.1 MB
constexpr size_t WS_WGB = WS_XG + XG_SZ;
constexpr size_t WS_WUB = WS_WGB + W_SZ;
constexpr size_t WS_WDB = WS_WUB + W_SZ;
constexpr size_t WS_ACT = WS_WDB + W_SZ;                  // 98 MB
constexpr size_t WS_Y   = WS_XG;                          // yseg overlays xg

typedef __attribute__((ext_vector_type(8))) short short8;
typedef __attribute__((ext_vector_type(4))) float f32x4;

#define GLOAD16(g, l) __builtin_amdgcn_global_load_lds( \
    (const __attribute__((address_space(1))) void*)(g), \
    (__attribute__((address_space(3))) void*)(l), 16, 0, 0)

static __device__ __forceinline__ short f2bf(float f) {
  return (short)__builtin_bit_cast(unsigned short, (__bf16)f);
}
static __device__ __forceinline__ float bf2f(short s) {
  return __builtin_bit_cast(float, ((unsigned)(unsigned short)s) << 16);
}

static __device__ __forceinline__ short8 pack8(const float* __restrict__ p) {
  float4 a = *(const float4*)p;
  float4 b = *(const float4*)(p + 4);
  short8 v;
  v[0] = f2bf(a.x); v[1] = f2bf(a.y); v[2] = f2bf(a.z); v[3] = f2bf(a.w);
  v[4] = f2bf(b.x); v[5] = f2bf(b.y); v[6] = f2bf(b.z); v[7] = f2bf(b.w);
  return v;
}

// ---------------- prep: wg+wu convert (blocks < 2*CONV1) + router ----------
#define W_ELEM ((size_t)NE * I_DIM * H_DIM)
#define W_CHUNK (W_ELEM / 8)                   // 2,883,584
#define CONV1 (int)(W_CHUNK / 256)             // 11,264 blocks per tensor
#define PREPB (2 * CONV1 + T_TOK / 4)

__global__ __launch_bounds__(256) void k_prep(const float* __restrict__ x,
                                              const float* __restrict__ gw,
                                              const float* __restrict__ wg,
                                              const float* __restrict__ wu,
                                              char* __restrict__ ws) {
  if (blockIdx.x < 2 * CONV1) {
    int which = blockIdx.x / CONV1;
    size_t off = ((size_t)(blockIdx.x - which * CONV1) * 256 + threadIdx.x) * 8;
    const float* src = which ? wu : wg;
    short* dst = (short*)(ws + (which ? WS_WUB : WS_WGB));
    *(short8*)(dst + off) = pack8(src + off);
    return;
  }
  int tid = threadIdx.x;
  int lane = tid & 63;
  int wv = tid >> 6;
  int t = (blockIdx.x - 2 * CONV1) * 4 + wv;

  float acc[NE];
#pragma unroll
  for (int e = 0; e < NE; ++e) acc[e] = 0.f;
  const float* xr = x + (size_t)t * H_DIM;
#pragma unroll
  for (int k = 0; k < H_DIM / 64; ++k) {
    float xv = xr[k * 64 + lane];
#pragma unroll
    for (int e = 0; e < NE; ++e) acc[e] += xv * gw[e * H_DIM + k * 64 + lane];
  }
#pragma unroll
  for (int e = 0; e < NE; ++e) {
#pragma unroll
    for (int off = 32; off; off >>= 1) acc[e] += __shfl_xor(acc[e], off);
  }

  __shared__ float s_ps[NE], s_c1[NE];
  __shared__ int s_rc[NE];
  if (tid < NE) { s_ps[tid] = 0.f; s_c1[tid] = 0.f; s_rc[tid] = 0; }
  __syncthreads();

  int* recIdx = (int*)(ws + WS_RECIDX);
  float* recW0 = (float*)(ws + WS_RECW0);
  float* recW1 = (float*)(ws + WS_RECW1);

  if (lane == 0) {
    float mx = acc[0];
#pragma unroll
    for (int e = 1; e < NE; ++e) mx = fmaxf(mx, acc[e]);
    float p[NE], s = 0.f;
#pragma unroll
    for (int e = 0; e < NE; ++e) { p[e] = expf(acc[e] - mx); s += p[e]; }
    float inv = 1.f / s;
#pragma unroll
    for (int e = 0; e < NE; ++e) p[e] *= inv;
    int i0 = 0;
#pragma unroll
    for (int e = 1; e < NE; ++e) if (p[e] > p[i0]) i0 = e;
    int i1 = (i0 == 0) ? 1 : 0;
#pragma unroll
    for (int e = 0; e < NE; ++e) if (e != i0 && p[e] > p[i1]) i1 = e;
    float w0 = p[i0], w1 = p[i1];
    float sm = fmaxf(w0 + w1, 1e-8f);
    w0 /= sm; w1 /= sm;
    recIdx[t] = i0 | (i1 << 8);
    recW0[t] = w0;
    recW1[t] = w1;
    atomicAdd(&s_c1[i0], 1.f);
#pragma unroll
    for (int e = 0; e < NE; ++e) atomicAdd(&s_ps[e], p[e]);
    atomicAdd(&s_rc[i0], 1);
    atomicAdd(&s_rc[i1], 1);
  }
  __syncthreads();
  if (tid < NE) {
    atomicAdd((float*)(ws + WS_PSUM) + tid, s_ps[tid]);
    atomicAdd((float*)(ws + WS_TOP1) + tid, s_c1[tid]);
    atomicAdd((int*)(ws + WS_ROUTE_CNT) + tid, s_rc[tid]);
  }
}

// ---------------- build: offsets + aux + assign (merged, single block) -----
__global__ __launch_bounds__(256) void k_build(char* __restrict__ ws,
                                               float* __restrict__ out_aux) {
  __shared__ int s_po[NE];
  __shared__ int s_cur[NE];
  int tid = threadIdx.x;
  if (tid == 0) {
    int* rc = (int*)(ws + WS_ROUTE_CNT);
    int* po = (int*)(ws + WS_PO);
    int acc = 0;
    for (int e = 0; e < NE; ++e) {
      s_po[e] = acc; po[e] = acc;
      acc += ((rc[e] + 127) / 128) * 128;
    }
    po[NE] = acc;
    float* c1 = (float*)(ws + WS_TOP1);
    float* ps = (float*)(ws + WS_PSUM);
    float aux = 0.f;
    for (int e = 0; e < NE; ++e)
      aux += (c1[e] / (float)T_TOK) * (ps[e] / (float)T_TOK);
    out_aux[0] = aux * (float)NE;
  }
  if (tid < NE) s_cur[tid] = 0;
  __syncthreads();

  int* recIdx = (int*)(ws + WS_RECIDX);
  int* tokid = (int*)(ws + WS_TOKID);
  int* pos0 = (int*)(ws + WS_POS0);
  int* pos1 = (int*)(ws + WS_POS1);
  for (int t = tid; t < T_TOK; t += 256) {
    int rec = recIdx[t];
    int e0 = rec & 255, e1 = (rec >> 8) & 255;
    int p0 = atomicAdd(&s_cur[e0], 1);
    int r0 = s_po[e0] + p0;
    tokid[r0] = t; pos0[t] = r0;
    int p1 = atomicAdd(&s_cur[e1], 1);
    int r1 = s_po[e1] + p1;
    tokid[r1] = t; pos1[t] = r1;
  }
}

// ---------------- gather x -> bf16 permuted (zero-padded) -------------------
__global__ __launch_bounds__(256) void k_gather(const float* __restrict__ x,
                                                char* __restrict__ ws) {
  const int* po = (const int*)(ws + WS_PO);
  const int* rc = (const int*)(ws + WS_ROUTE_CNT);
  const int* tokid = (const int*)(ws + WS_TOKID);
  short* xg = (short*)(ws + WS_XG);
  int r = blockIdx.x * 8 + (threadIdx.x >> 5);
  if (r >= po[NE]) return;
  int e = 0;
#pragma unroll
  for (int q = 1; q < NE; ++q) if (r >= po[q]) e = q;
  int l = r - po[e];
  int c0 = (threadIdx.x & 31) * 32;
  short* dst = xg + (size_t)r * H_DIM + c0;
  if (l < rc[e]) {
    const float* src = x + (size_t)tokid[r] * H_DIM + c0;
#pragma unroll
    for (int j = 0; j < 4; ++j) *(short8*)(dst + j * 8) = pack8(src + j * 8);
  } else {
    short8 z = (short8)0;
#pragma unroll
    for (int j = 0; j < 4; ++j) *(short8*)(dst + j * 8) = z;
  }
}

// ============ fused FFN1: act = silu(xg@wg^T) * (xg@wu^T) (R17, frozen) ====
// Dual-B m97-family loop: A staged ONCE for both B streams; 32 MFMA/wave per
// K-step on 12 staged gloads; no act re-read for the silu merge. 48 KB LDS +
// ~195 unified regs at (256,2) -> 2 blocks/CU. Trailing NCONV blocks convert
// wd f32->bf16 under this dispatch's spare bandwidth.
template <int NCONV>
__global__ __launch_bounds__(256, 2) void k_ffn1(const short* __restrict__ A,
                                                 const short* __restrict__ Bg_,
                                                 const short* __restrict__ Bu_,
                                                 short* __restrict__ act,
                                                 const float* __restrict__ cw,
                                                 char* __restrict__ ws) {
  constexpr int GEMMB = 8 * 17 * (I_DIM / 128);
  if (NCONV > 0 && blockIdx.x >= GEMMB) {
    int cidx = blockIdx.x - GEMMB;
    size_t off = ((size_t)cidx * 256 + threadIdx.x) * 8;
    short* dst = (short*)(ws + WS_WDB);
    *(short8*)(dst + off) = pack8(cw + off);
    return;
  }

  const int* po = (const int*)(ws + WS_PO);
  int poNE = po[NE];

  int idx = blockIdx.x;
  int xcd = idx & 7, j = idx >> 3;
  int nt = j / 17;
  int rt = xcd * 17 + (j - nt * 17);

  int r0 = rt * 128;
  if (r0 >= poNE) return;
  int e = 0;
#pragma unroll
  for (int qe = 1; qe < NE; ++qe) if (r0 >= po[qe]) e = qe;

  const short* Ab = A + (size_t)r0 * H_DIM;
  const short* Gb = Bg_ + (size_t)e * ((size_t)I_DIM * H_DIM) + (size_t)(nt * 128) * H_DIM;
  const short* Ub = Bu_ + (size_t)e * ((size_t)I_DIM * H_DIM) + (size_t)(nt * 128) * H_DIM;

  __shared__ __align__(16) short As[128 * 64];
  __shared__ __align__(16) short Gs[128 * 64];
  __shared__ __align__(16) short Us[128 * 64];

  int tid = threadIdx.x, lane = tid & 63, w = tid >> 6;
  int wr = (w >> 1) * 64, wc = (w & 1) * 64;
  int fr = lane & 15, kq = (lane >> 4) * 8;
  int srow = tid >> 3, scol = (tid & 7) * 8;

  f32x4 accg[4][4], accu[4][4];
  f32x4 z4 = {0.f, 0.f, 0.f, 0.f};
#pragma unroll
  for (int m = 0; m < 4; ++m)
#pragma unroll
    for (int n = 0; n < 4; ++n) { accg[m][n] = z4; accu[m][n] = z4; }

  for (int kk = 0; kk < H_DIM; kk += 64) {
#pragma unroll
    for (int c = 0; c < 4; ++c) {
      GLOAD16(Ab + (size_t)(c * 32 + srow) * H_DIM + kk + scol, &As[c * 2048 + tid * 8]);
      GLOAD16(Gb + (size_t)(c * 32 + srow) * H_DIM + kk + scol, &Gs[c * 2048 + tid * 8]);
      GLOAD16(Ub + (size_t)(c * 32 + srow) * H_DIM + kk + scol, &Us[c * 2048 + tid * 8]);
    }
    __syncthreads();
#pragma unroll
    for (int ks = 0; ks < 2; ++ks) {
      short8 af[4];
#pragma unroll
      for (int m = 0; m < 4; ++m)
        af[m] = *(const short8*)&As[(wr + m * 16 + fr) * 64 + ks * 32 + kq];
#pragma unroll
      for (int n = 0; n < 4; ++n) {
        short8 bg = *(const short8*)&Gs[(wc + n * 16 + fr) * 64 + ks * 32 + kq];
        short8 bu = *(const short8*)&Us[(wc + n * 16 + fr) * 64 + ks * 32 + kq];
#pragma unroll
        for (int m = 0; m < 4; ++m) {
          accg[m][n] = __builtin_amdgcn_mfma_f32_16x16x32_bf16(af[m], bg, accg[m][n], 0, 0, 0);
          accu[m][n] = __builtin_amdgcn_mfma_f32_16x16x32_bf16(af[m], bu, accu[m][n], 0, 0, 0);
        }
      }
    }
    __syncthreads();
  }

  int q4 = (lane >> 4) * 4;
#pragma unroll
  for (int m = 0; m < 4; ++m) {
#pragma unroll
    for (int n = 0; n < 4; ++n) {
      int col = nt * 128 + wc + n * 16 + fr;
#pragma unroll
      for (int j2 = 0; j2 < 4; ++j2) {
        float g = accg[m][n][j2];
        float u = accu[m][n][j2];
        act[(size_t)(r0 + wr + m * 16 + q4 + j2) * I_DIM + col] =
            f2bf(g / (1.f + expf(-g)) * u);
      }
    }
  }
}

// ============ m97-exact 128x128xBK64 GEMM (down projection, R17) ===========
__global__ __launch_bounds__(256, 4) void k_down(const short* __restrict__ A,
                                                 const short* __restrict__ Bw,
                                                 short* __restrict__ Cb,
                                                 char* __restrict__ ws) {
  const int* po = (const int*)(ws + WS_PO);
  int poNE = po[NE];

  int idx = blockIdx.x;
  int xcd = idx & 7, j = idx >> 3;
  int nt = j / 17;
  int rt = xcd * 17 + (j - nt * 17);

  int r0 = rt * 128;
  if (r0 >= poNE) return;
  int e = 0;
#pragma unroll
  for (int qe = 1; qe < NE; ++qe) if (r0 >= po[qe]) e = qe;

  const short* Ab = A + (size_t)r0 * I_DIM;
  const short* Bb = Bw + (size_t)e * ((size_t)H_DIM * I_DIM) + (size_t)(nt * 128) * I_DIM;

  __shared__ __align__(16) short As[128 * 64];
  __shared__ __align__(16) short Bs[128 * 64];

  int tid = threadIdx.x, lane = tid & 63, w = tid >> 6;
  int wr = (w >> 1) * 64, wc = (w & 1) * 64;
  int fr = lane & 15, kq = (lane >> 4) * 8;
  int srow = tid >> 3, scol = (tid & 7) * 8;

  f32x4 acc[4][4];
  f32x4 z4 = {0.f, 0.f, 0.f, 0.f};
#pragma unroll
  for (int m = 0; m < 4; ++m)
#pragma unroll
    for (int n = 0; n < 4; ++n) acc[m][n] = z4;

  for (int kk = 0; kk < I_DIM; kk += 64) {
#pragma unroll
    for (int c = 0; c < 4; ++c) {
      GLOAD16(Ab + (size_t)(c * 32 + srow) * I_DIM + kk + scol, &As[c * 2048 + tid * 8]);
      GLOAD16(Bb + (size_t)(c * 32 + srow) * I_DIM + kk + scol, &Bs[c * 2048 + tid * 8]);
    }
    __syncthreads();
#pragma unroll
    for (int ks = 0; ks < 2; ++ks) {
      short8 af[4];
#pragma unroll
      for (int m = 0; m < 4; ++m)
        af[m] = *(const short8*)&As[(wr + m * 16 + fr) * 64 + ks * 32 + kq];
#pragma unroll
      for (int n = 0; n < 4; ++n) {
        short8 bf_ = *(const short8*)&Bs[(wc + n * 16 + fr) * 64 + ks * 32 + kq];
#pragma unroll
        for (int m = 0; m < 4; ++m)
          acc[m][n] = __builtin_amdgcn_mfma_f32_16x16x32_bf16(af[m], bf_, acc[m][n], 0, 0, 0);
      }
    }
    __syncthreads();
  }

  int q4 = (lane >> 4) * 4;
#pragma unroll
  for (int m = 0; m < 4; ++m) {
#pragma unroll
    for (int n = 0; n < 4; ++n) {
      int col = nt * 128 + wc + n * 16 + fr;
#pragma unroll
      for (int j2 = 0; j2 < 4; ++j2)
        Cb[(size_t)(r0 + wr + m * 16 + q4 + j2) * H_DIM + col] = f2bf(acc[m][n][j2]);
    }
  }
}

// ---------------- combine: out[t] = w0*y[pos0] + w1*y[pos1] ----------------
__global__ __launch_bounds__(256) void k_combine(float* __restrict__ out,
                                                 char* __restrict__ ws) {
  int t = blockIdx.x * 4 + (threadIdx.x >> 6);
  int lane = threadIdx.x & 63;
  const float* recW0 = (const float*)(ws + WS_RECW0);
  const float* recW1 = (const float*)(ws + WS_RECW1);
  const int* pos0 = (const int*)(ws + WS_POS0);
  const int* pos1 = (const int*)(ws + WS_POS1);
  const short* yseg = (const short*)(ws + WS_Y);

  float w0 = recW0[t], w1 = recW1[t];
  const short* y0 = yseg + (size_t)pos0[t] * H_DIM + lane * 16;
  const short* y1 = yseg + (size_t)pos1[t] * H_DIM + lane * 16;
  float* op = out + (size_t)t * H_DIM + lane * 16;

  short8 a0 = *(const short8*)y0;
  short8 a1 = *(const short8*)(y0 + 8);
  short8 b0 = *(const short8*)y1;
  short8 b1 = *(const short8*)(y1 + 8);
#pragma unroll
  for (int j = 0; j < 8; ++j)
    op[j] = w0 * bf2f(a0[j]) + w1 * bf2f(b0[j]);
#pragma unroll
  for (int j = 0; j < 8; ++j)
    op[8 + j] = w0 * bf2f(a1[j]) + w1 * bf2f(b1[j]);
}

extern "C" void kernel_launch(void* const* d_in, const int* in_sizes, int n_in,
                              void* d_out, int out_size, void* d_ws, size_t ws_size,
                              hipStream_t stream) {
  const float* x  = (const float*)d_in[0];
  const float* gw = (const float*)d_in[1];
  const float* wg = (const float*)d_in[2];
  const float* wu = (const float*)d_in[3];
  const float* wd = (const float*)d_in[4];
  float* out = (float*)d_out;
  char* ws = (char*)d_ws;

  hipMemsetAsync(ws, 0, 256, stream);

  const short* xg  = (const short*)(ws + WS_XG);
  const short* wgb = (const short*)(ws + WS_WGB);
  const short* wub = (const short*)(ws + WS_WUB);
  const short* wdb = (const short*)(ws + WS_WDB);
  short* act  = (short*)(ws + WS_ACT);
  short* yseg = (short*)(ws + WS_Y);

  // prep: wg + wu convert + router (wd rides on FFN1)
  k_prep<<<PREPB, 256, 0, stream>>>(x, gw, wg, wu, ws);
  k_build<<<1, 256, 0, stream>>>(ws, out + (size_t)T_TOK * H_DIM);
  k_gather<<<RMAX / 8, 256, 0, stream>>>(x, ws);

  // fused FFN1: act = silu(xg@wg^T)*(xg@wu^T)  (+ trailing wd convert)
  k_ffn1<1><<<8 * 17 * (I_DIM / 128) + CONV1, 256, 0, stream>>>(
      xg, wgb, wub, act, wd, ws);
  // down: yseg = act @ wd^T
  k_down<<<8 * 17 * (H_DIM / 128), 256, 0, stream>>>(act, wdb, yseg, ws);

  k_combine<<<T_TOK / 4, 256, 0, stream>>>(out, ws);
}